// Round 1
// baseline (686.104 us; speedup 1.0000x reference)
//
#include <hip/hip_runtime.h>
#include <hip/hip_bf16.h>
#include <math.h>

// Shapes: x(32,256,128,128) f32, W1(64,256), W2(256,64), W3(2,256), b3(2)
// out: (32,2) f32.
// Identity used: mean(x * gate[:, :, None, None], (2,3)) == gate * mean(x, (2,3))
// -> x is read exactly once (512 MiB) => memory-bound, floor ~82us @6.3TB/s.

#define HW 16384        // 128*128
#define C 256
#define CR 64
#define B 32

// ---- Kernel 1: per-(b,c)-plane mean. 8192 blocks x 256 threads. ----
__global__ __launch_bounds__(256) void pool_kernel(const float* __restrict__ x,
                                                   float* __restrict__ f0) {
    const int plane = blockIdx.x;                 // b*C + c
    const float4* p = (const float4*)(x + (size_t)plane * HW);
    const int tid = threadIdx.x;
    float s = 0.f;
#pragma unroll
    for (int i = 0; i < 16; ++i) {
        float4 v = p[i * 256 + tid];              // coalesced, 16B/lane
        s += (v.x + v.y) + (v.z + v.w);
    }
    // wave64 reduce
#pragma unroll
    for (int off = 32; off > 0; off >>= 1) s += __shfl_down(s, off, 64);
    __shared__ float ws[4];
    if ((tid & 63) == 0) ws[tid >> 6] = s;
    __syncthreads();
    if (tid == 0) {
        f0[plane] = (ws[0] + ws[1] + ws[2] + ws[3]) * (1.0f / (float)HW);
    }
}

// ---- Kernel 2: tiny SE-MLP + final linear. 32 blocks x 256 threads. ----
__global__ __launch_bounds__(256) void mlp_kernel(const float* __restrict__ f0,
                                                  const float* __restrict__ W1,
                                                  const float* __restrict__ W2,
                                                  const float* __restrict__ W3,
                                                  const float* __restrict__ b3,
                                                  float* __restrict__ out) {
    const int b = blockIdx.x;                     // 0..31
    const int tid = threadIdx.x;                  // 0..255
    __shared__ float f0s[C];
    __shared__ float f1s[CR];
    __shared__ float ps[C];
    __shared__ float red[2][4];

    f0s[tid] = f0[b * C + tid];
    __syncthreads();

    // f1[j] = relu(dot(f0s, W1[j,:])), j in [0,64)
    if (tid < CR) {
        const float* w = W1 + tid * C;
        float acc = 0.f;
#pragma unroll 8
        for (int i = 0; i < C; ++i) acc = fmaf(f0s[i], w[i], acc);
        f1s[tid] = fmaxf(acc, 0.f);
    }
    __syncthreads();

    // p[c] = sigmoid(dot(f1s, W2[c,:])) * f0s[c]
    {
        const float* w = W2 + tid * CR;
        float acc = 0.f;
#pragma unroll
        for (int i = 0; i < CR; ++i) acc = fmaf(f1s[i], w[i], acc);
        float g = 1.0f / (1.0f + expf(-acc));
        ps[tid] = g * f0s[tid];
    }
    __syncthreads();

    // out[b][o] = dot(ps, W3[o,:]) + b3[o], o in {0,1}; block-wide reduce
#pragma unroll
    for (int o = 0; o < 2; ++o) {
        float v = ps[tid] * W3[o * C + tid];
#pragma unroll
        for (int off = 32; off > 0; off >>= 1) v += __shfl_down(v, off, 64);
        if ((tid & 63) == 0) red[o][tid >> 6] = v;
    }
    __syncthreads();
    if (tid < 2) {
        out[b * 2 + tid] = red[tid][0] + red[tid][1] + red[tid][2] + red[tid][3] + b3[tid];
    }
}

extern "C" void kernel_launch(void* const* d_in, const int* in_sizes, int n_in,
                              void* d_out, int out_size, void* d_ws, size_t ws_size,
                              hipStream_t stream) {
    const float* x  = (const float*)d_in[0];
    const float* W1 = (const float*)d_in[1];
    const float* W2 = (const float*)d_in[2];
    const float* W3 = (const float*)d_in[3];
    const float* b3 = (const float*)d_in[4];
    float* out = (float*)d_out;
    float* f0  = (float*)d_ws;                    // 8192 floats = 32 KiB

    pool_kernel<<<B * C, 256, 0, stream>>>(x, f0);
    mlp_kernel<<<B, 256, 0, stream>>>(f0, W1, W2, W3, b3, out);
}